// Round 9
// baseline (130.286 us; speedup 1.0000x reference)
//
#include <hip/hip_runtime.h>
#include <math.h>

#define BS 256
#define GTMAX 64
#define KMAX 1024
#define CHUNK 512
#define NB1 512          // pass1 chunk blocks (block NB1 = det head)
#define NB2 512          // k_main RPN blocks (blocks >= NB2 are tail role)
#define MS 28
#define MSQ (MS*MS)

// Pinned-op IoU: bit-identical wherever inlined (force_pos float equality).
__device__ __forceinline__ float box_area(float4 b) {
    return __fmul_rn(__fsub_rn(b.z, b.x), __fsub_rn(b.w, b.y));
}
__device__ __forceinline__ float iou_f(float4 a, float areaA, float4 b, float areaB) {
    float lx = fmaxf(a.x, b.x), ly = fmaxf(a.y, b.y);
    float rx = fminf(a.z, b.z), ry = fminf(a.w, b.w);
    float w = fmaxf(__fsub_rn(rx, lx), 0.0f);
    float h = fmaxf(__fsub_rn(ry, ly), 0.0f);
    float inter = __fmul_rn(w, h);
    float den = __fsub_rn(__fadd_rn(areaA, areaB), inter);
    return __fdividef(inter, den);
}
__device__ __forceinline__ float sl1(float x) {
    float ax = fabsf(x);
    return ax < 1.0f ? 0.5f * ax * ax : ax - 0.5f;
}
__device__ __forceinline__ float bce(float l, float t) {
    return fmaxf(l, 0.0f) - l * t + log1pf(expf(-fabsf(l)));
}

struct ShA { float4 abox[CHUNK]; float aarea[CHUNK]; };                       // 10240 B
struct ShD { float miou[KMAX]; unsigned char gi[KMAX]; short pl[KMAX]; };     //  7168 B

// acc: 4 det_ce, 5 det_sel, 6 det_reg, 7 det_selfg, 8 vis_sum, 9 amo_sum, 10 keep_cnt

// Blocks 0..NB1-1: per-gt max IoU over anchor range -> bmaxT[b][gt] (plain stores;
// published by kernel-boundary flush). Block NB1: det matching + fg/bg wave-scan
// selection -> pinfo, acc[5,7,10]; zeroes acc[4,6,8,9] for k_main's tail role.
__global__ __launch_bounds__(BS) void k_pass1(
    const float4* __restrict__ anchors, const float4* __restrict__ gt,
    const int* __restrict__ gt_labels, const float4* __restrict__ proposals,
    int N, int M, int K, int AP,
    float* __restrict__ bmaxT, float* acc, int* pinfo)
{
    __shared__ __align__(16) char shbuf[sizeof(ShA)];
    __shared__ float4 sgt[GTMAX];
    __shared__ float sarea[GTMAX];
    __shared__ int   slab[GTMAX];
    __shared__ float swm[4 * 64];
    __shared__ float sred[4];
    __shared__ int   swtot[4];
    ShA* SA = (ShA*)shbuf;
    ShD* SD = (ShD*)shbuf;

    const int b = blockIdx.x, t = threadIdx.x;
    const int wave = t >> 6, lane = t & 63;

    if (t < M) {
        float4 g = gt[t];
        sgt[t] = g; sarea[t] = box_area(g); slab[t] = gt_labels[t];
    }
    __syncthreads();

    if (b < NB1) {
        // ---------- per-gt max over this block's anchor range ----------
        int base = b * AP;
        int end = min(N, base + AP);
        float4 g; float ga = 0.0f;
        bool gok = lane < M;
        if (gok) { g = sgt[lane]; ga = sarea[lane]; }
        float m = 0.0f;                          // IoU >= 0 always
        for (int tile = base; tile < end; tile += CHUNK) {
            int tcnt = min(CHUNK, end - tile);
            __syncthreads();
            for (int k = t; k < tcnt; k += BS) {
                float4 a = anchors[tile + k];
                SA->abox[k] = a;
                SA->aarea[k] = box_area(a);
            }
            __syncthreads();
            for (int k = wave; k < tcnt; k += 4) {   // wave-uniform broadcast
                float4 a = SA->abox[k];
                float aa = SA->aarea[k];
                if (gok) m = fmaxf(m, iou_f(a, aa, g, ga));
            }
        }
        swm[wave * 64 + lane] = m;
        __syncthreads();
        if (wave == 0) {
            float mm = fmaxf(fmaxf(swm[lane], swm[64 + lane]),
                             fmaxf(swm[128 + lane], swm[192 + lane]));
            bmaxT[b * GTMAX + lane] = mm;        // plain store; kernel-boundary flush
        }
    } else {
        // ---------- det matching + sampling (single block) ----------
        for (int p = t; p < K; p += BS) {
            float4 a = proposals[p];
            float areaA = box_area(a);
            float mx = -1.0f; int am = 0;
            for (int j = 0; j < M; ++j) {
                float v = iou_f(a, areaA, sgt[j], sarea[j]);
                if (v > mx) { mx = v; am = j; }
            }
            SD->miou[p] = mx; SD->gi[p] = (unsigned char)am;
            int pl = slab[am];
            if (mx < 0.5f) pl = 0;
            if (mx < 0.1f) pl = -1;
            SD->pl[p] = (short)pl;
        }
        __syncthreads();
        // wave-scan fg/bg sampling (4 contiguous p per thread)
        int myp0 = t * 4;
        int cf = 0, cb = 0;
        for (int e = 0; e < 4; ++e) {
            int p = myp0 + e;
            if (p < K) { int pl = SD->pl[p]; cf += (pl > 0); cb += (pl == 0); }
        }
        int packed = cf | (cb << 16);
        int scan = packed;
        for (int off = 1; off < 64; off <<= 1) {
            int n = __shfl_up(scan, off);
            if (lane >= off) scan += n;
        }
        if (lane == 63) swtot[wave] = scan;
        __syncthreads();
        int woff = 0, tot = 0;
        for (int w = 0; w < 4; ++w) { int v = swtot[w]; if (w < wave) woff += v; tot += v; }
        int excl = scan - packed + woff;
        int runf = excl & 0xffff, runb = (excl >> 16) & 0xffff;
        int totfg = tot & 0xffff, totbg = (tot >> 16) & 0xffff;
        int nfg = totfg < 32 ? totfg : 32;
        int nbg = 128 - nfg;
        int keeploc = 0;
        for (int e = 0; e < 4; ++e) {
            int p = myp0 + e;
            if (p < K) {
                int pl = SD->pl[p];
                int sf = 0, sb = 0;
                if (pl > 0)       { runf++; sf = (runf <= nfg); }
                else if (pl == 0) { runb++; sb = (runb <= nbg); }
                int kp = SD->miou[p] >= 0.5f ? 1 : 0;
                keeploc += kp;
                int lab = pl > 0 ? pl : 0;
                pinfo[p] = (int)SD->gi[p] | (lab << 6) | (sf << 13) | (sb << 14) | (kp << 15);
            }
        }
        for (int off = 32; off; off >>= 1) keeploc += __shfl_xor(keeploc, off);
        if (lane == 0) sred[wave] = (float)keeploc;
        __syncthreads();
        if (t == 0) {
            acc[7]  = (float)nfg;
            acc[5]  = (float)(nfg + (totbg < nbg ? totbg : nbg));
            acc[10] = sred[0] + sred[1] + sred[2] + sred[3];
            acc[4] = 0.0f; acc[6] = 0.0f; acc[8] = 0.0f; acc[9] = 0.0f;
        }
    }
}

// Fused main kernel (round-6-proven structure).
// Blocks < NB2 (RPN role): reduce bmaxT -> smaxpg, grid-stride RPN loss -> ppart.
// Blocks >= NB2 (tail role, p = b - NB2): det CE (parallel over C), det reg,
//   mask loss, accumulated via device atomicAdd into acc[4,6,8,9].
__global__ __launch_bounds__(BS) void k_main(
    const float4* __restrict__ anchors, const float4* __restrict__ preds,
    const float2* __restrict__ cls, const float4* __restrict__ gt,
    int N, int M, int K, int C, int H,
    const float* __restrict__ bmaxT, float* __restrict__ ppart,
    const float* __restrict__ vism, const float* __restrict__ amom,
    const float* __restrict__ mvl, const float* __restrict__ mal,
    const float4* __restrict__ proposals, const int* __restrict__ pinfo,
    const float* __restrict__ roi_cls, const float* __restrict__ roi_deltas,
    const int* __restrict__ gt_labels, float* acc)
{
    const int b = blockIdx.x, t = threadIdx.x;
    const int wave = t >> 6, lane = t & 63;

    if (b < NB2) {
        // ================= RPN role =================
        __shared__ float4 sgt[GTMAX];
        __shared__ float2 sgp[GTMAX];        // .x = area, .y = gmax
        __shared__ float swm[256];
        __shared__ float sacc[4];
        float4 gg; float garea = 0.0f;
        if (t < M) {
            gg = gt[t];
            garea = box_area(gg);
            sgt[t] = gg;
        }
        // per-block gmax reduction from bmaxT (L2/L3-hot, coalesced; proven r6)
        {
            int j = t & 63, part = t >> 6;
            float mm = 0.0f;
            int r0 = part * (NB1 / 4);
            for (int i = r0; i < r0 + NB1 / 4; ++i)
                mm = fmaxf(mm, bmaxT[i * GTMAX + j]);
            swm[t] = mm;
        }
        if (t < 4) sacc[t] = 0.0f;
        __syncthreads();
        if (t < M) {
            float mm = fmaxf(fmaxf(swm[t], swm[64 + t]),
                             fmaxf(swm[128 + t], swm[192 + t]));
            sgp[t] = make_float2(garea, mm);
        }
        __syncthreads();

        float ce = 0.f, valid = 0.f, pos = 0.f, reg = 0.f;
        for (int i = b * BS + t; i < N; i += NB2 * BS) {
            float4 a = anchors[i];
            float areaA = box_area(a);
            float2 x = cls[i];                    // hoisted
            float maxiou = -1.0f; bool force = false;
            // hot loop: no argmax bookkeeping (deferred below, rare path)
            for (int j = 0; j < M; ++j) {
                float2 gp = sgp[j];
                float v = iou_f(a, areaA, sgt[j], gp.x);
                maxiou = fmaxf(maxiou, v);
                force = force || (v == gp.y);
            }
            int label = force ? 1 : (maxiou >= 0.7f ? 1 : (maxiou <= 0.3f ? 0 : -1));
            if (label >= 0) {
                valid += 1.0f;
                float m = fmaxf(x.x, x.y);
                float lse = m + __logf(__expf(x.x - m) + __expf(x.y - m));
                ce += lse - (label == 1 ? x.y : x.x);
            }
            if (label == 1) {
                pos += 1.0f;
                // recompute first-max argmax (bit-identical iou_f -> same arg)
                int arg = 0;
                for (int j = 0; j < M; ++j) {
                    float v = iou_f(a, areaA, sgt[j], sgp[j].x);
                    if (v == maxiou) { arg = j; break; }
                }
                float4 g = sgt[arg];
                float rw = a.z - a.x, rh = a.w - a.y;
                float t0 = ((g.x + g.z) * 0.5f - (a.x + a.z) * 0.5f) / rw;
                float t1 = ((g.y + g.w) * 0.5f - (a.y + a.w) * 0.5f) / rh;
                float t2 = logf((g.z - g.x) / rw);
                float t3 = logf((g.w - g.y) / rh);
                float4 p = preds[i];
                reg += sl1(p.x - t0) + sl1(p.y - t1) + sl1(p.z - t2) + sl1(p.w - t3);
            }
        }
        for (int off = 32; off; off >>= 1) {
            ce += __shfl_xor(ce, off); valid += __shfl_xor(valid, off);
            pos += __shfl_xor(pos, off); reg += __shfl_xor(reg, off);
        }
        if (lane == 0) {
            atomicAdd(&sacc[0], ce); atomicAdd(&sacc[1], valid);
            atomicAdd(&sacc[2], reg); atomicAdd(&sacc[3], pos);
        }
        __syncthreads();
        if (t == 0) {
            ppart[0 * NB2 + b] = sacc[0];
            ppart[1 * NB2 + b] = sacc[1];
            ppart[2 * NB2 + b] = sacc[2];
            ppart[3 * NB2 + b] = sacc[3];
        }
    } else {
        // ================= tail role: proposal p =================
        __shared__ float sredM[4], sredE[4];
        int p = b - NB2;
        if (p >= K) return;
        int info = pinfo[p];
        bool sf = (info >> 13) & 1, sb = (info >> 14) & 1, kp = (info >> 15) & 1;
        if (!(sf | sb | kp)) return;
        int gi = info & 63;
        int lab = (info >> 6) & 0x7f;

        if (sf || sb) {   // detection CE, parallel over classes
            const float* row = roi_cls + (size_t)p * C;
            float v = (t < C) ? row[t] : -INFINITY;
            float m = v;
            for (int off = 32; off; off >>= 1) m = fmaxf(m, __shfl_xor(m, off));
            if (lane == 0) sredM[wave] = m;
            __syncthreads();
            m = fmaxf(fmaxf(sredM[0], sredM[1]), fmaxf(sredM[2], sredM[3]));
            float e = (t < C) ? __expf(v - m) : 0.0f;
            for (int off = 32; off; off >>= 1) e += __shfl_xor(e, off);
            if (lane == 0) sredE[wave] = e;
            __syncthreads();
            if (t == 0) {
                float lse = m + __logf(sredE[0] + sredE[1] + sredE[2] + sredE[3]);
                atomicAdd(&acc[4], lse - row[lab]);
            }
        }
        if (sf && t == 0) {   // detection reg
            float4 a = proposals[p];
            float4 g = gt[gi];
            float rw = a.z - a.x, rh = a.w - a.y;
            float t0 = ((g.x + g.z) * 0.5f - (a.x + a.z) * 0.5f) / rw;
            float t1 = ((g.y + g.w) * 0.5f - (a.y + a.w) * 0.5f) / rh;
            float t2 = logf((g.z - g.x) / rw);
            float t3 = logf((g.w - g.y) / rh);
            const float* pr = roi_deltas + ((size_t)p * C + lab) * 4;
            float r = sl1(pr[0] - t0) + sl1(pr[1] - t1) + sl1(pr[2] - t2) + sl1(pr[3] - t3);
            atomicAdd(&acc[6], r);
        }
        if (kp) {   // mask loss (bilinear roi-align + bce)
            int mlab = gt_labels[gi];
            float4 r = proposals[p];
            float x1 = r.x - 0.5f, y1 = r.y - 0.5f;
            float bw = (r.z - r.x) / (float)MS;
            float bh = (r.w - r.y) / (float)MS;
            const float* vm = vism + (size_t)gi * H * H;
            const float* am = amom + (size_t)gi * H * H;
            const float* lv = mvl + ((size_t)p * C + mlab) * MSQ;
            const float* la = mal + ((size_t)p * C + mlab) * MSQ;
            float sv = 0.f, sa = 0.f;
            for (int px = t; px < MSQ; px += BS) {
                int gx = px % MS, gy = px / MS;
                float X = x1 + ((float)gx + 0.5f) * bw;
                float Y = y1 + ((float)gy + 0.5f) * bh;
                bool valid = (Y > -1.0f) && (Y < (float)H) && (X > -1.0f) && (X < (float)H);
                float Yc = fminf(fmaxf(Y, 0.0f), (float)(H - 1));
                float Xc = fminf(fmaxf(X, 0.0f), (float)(H - 1));
                int y0 = (int)floorf(Yc), x0 = (int)floorf(Xc);
                int y1i = min(y0 + 1, H - 1), x1i = min(x0 + 1, H - 1);
                float ly = Yc - (float)y0, lx = Xc - (float)x0;
                float w00 = (1.f - ly) * (1.f - lx), w01 = (1.f - ly) * lx;
                float w10 = ly * (1.f - lx), w11 = ly * lx;
                float tv = vm[y0 * H + x0] * w00 + vm[y0 * H + x1i] * w01 +
                           vm[y1i * H + x0] * w10 + vm[y1i * H + x1i] * w11;
                float ta = am[y0 * H + x0] * w00 + am[y0 * H + x1i] * w01 +
                           am[y1i * H + x0] * w10 + am[y1i * H + x1i] * w11;
                if (!valid) { tv = 0.f; ta = 0.f; }
                sv += bce(lv[px], tv);
                sa += bce(la[px], ta);
            }
            for (int off = 32; off; off >>= 1) {
                sv += __shfl_xor(sv, off);
                sa += __shfl_xor(sa, off);
            }
            if (lane == 0) { sredM[wave] = sv; sredE[wave] = sa; }
            __syncthreads();
            if (t == 0) {
                atomicAdd(&acc[8], sredM[0] + sredM[1] + sredM[2] + sredM[3]);
                atomicAdd(&acc[9], sredE[0] + sredE[1] + sredE[2] + sredE[3]);
            }
        }
    }
}

// Sum rpn partials (wave w owns quantity q=w) and combine all losses.
__global__ __launch_bounds__(BS) void k_final(
    const float* __restrict__ ppart, const float* __restrict__ acc, float* out)
{
    __shared__ float sq[4];
    int t = threadIdx.x;
    int wave = t >> 6, lane = t & 63;
    float s = 0.f;
    for (int b = lane; b < NB2; b += 64) s += ppart[wave * NB2 + b];
    for (int off = 32; off; off >>= 1) s += __shfl_xor(s, off);
    if (lane == 0) sq[wave] = s;
    __syncthreads();
    if (t == 0) {
        float rpn_cls = sq[0] / fmaxf(sq[1], 1.0f);
        float rpn_reg = sq[2] / fmaxf(sq[3] * 4.0f, 1.0f);
        float det_cls = acc[4] / fmaxf(acc[5], 1.0f);
        float det_reg = acc[6] / fmaxf(acc[7] * 4.0f, 1.0f);
        float den = fmaxf(acc[10], 1.0f) * (float)MSQ;
        out[0] = rpn_cls + rpn_reg + det_cls + det_reg + acc[8] / den + acc[9] / den;
    }
}

extern "C" void kernel_launch(void* const* d_in, const int* in_sizes, int n_in,
                              void* d_out, int out_size, void* d_ws, size_t ws_size,
                              hipStream_t stream) {
    const float2* rpn_cls   = (const float2*)d_in[0];
    const float4* rpn_pred  = (const float4*)d_in[1];
    const float4* anchors   = (const float4*)d_in[2];
    const float4* gt        = (const float4*)d_in[3];
    const int*    gt_labels = (const int*)d_in[4];
    const float*  roi_cls   = (const float*)d_in[5];
    const float*  roi_deltas= (const float*)d_in[6];
    const float4* proposals = (const float4*)d_in[7];
    const float*  mvl       = (const float*)d_in[8];
    const float*  mal       = (const float*)d_in[9];
    const float*  vism      = (const float*)d_in[10];
    const float*  amom      = (const float*)d_in[11];

    int N = in_sizes[0] / 2;
    int M = in_sizes[3] / 4;
    int K = in_sizes[7] / 4;
    int C = in_sizes[5] / K;
    int HW = in_sizes[10] / M;
    int H = (int)(sqrt((double)HW) + 0.5);

    float* wsf   = (float*)d_ws;
    float* acc   = wsf;                          // 16 floats
    float* ppart = wsf + 16;                     // 4*NB2 = 2048
    float* bmaxT = wsf + 16 + 4 * NB2;           // NB1*64 = 32768
    int*   pinfo = (int*)(bmaxT + NB1 * GTMAX);  // K ints
    float* out   = (float*)d_out;

    int AP = (N + NB1 - 1) / NB1;                // anchors per pass1 block

    k_pass1<<<NB1 + 1, BS, 0, stream>>>(anchors, gt, gt_labels, proposals,
                                        N, M, K, AP, bmaxT, acc, pinfo);
    k_main<<<NB2 + K, BS, 0, stream>>>(anchors, rpn_pred, rpn_cls, gt,
                                       N, M, K, C, H, bmaxT, ppart,
                                       vism, amom, mvl, mal, proposals, pinfo,
                                       roi_cls, roi_deltas, gt_labels, acc);
    k_final<<<1, BS, 0, stream>>>(ppart, acc, out);
}

// Round 10
// 102.567 us; speedup vs baseline: 1.2702x; 1.2702x over previous
//
#include <hip/hip_runtime.h>
#include <math.h>

#define BS 256
#define GTMAX 64
#define KMAX 1024
#define CHUNK 512
#define NB1 512          // pass1 chunk blocks (block NB1 = det head)
#define NB2 512          // k_main RPN blocks (blocks >= NB2 are tail role)
#define TPB 4            // tail proposals per block
#define MS 28
#define MSQ (MS*MS)

// Pinned-op IoU: bit-identical wherever inlined (force_pos float equality).
__device__ __forceinline__ float box_area(float4 b) {
    return __fmul_rn(__fsub_rn(b.z, b.x), __fsub_rn(b.w, b.y));
}
__device__ __forceinline__ float iou_f(float4 a, float areaA, float4 b, float areaB) {
    float lx = fmaxf(a.x, b.x), ly = fmaxf(a.y, b.y);
    float rx = fminf(a.z, b.z), ry = fminf(a.w, b.w);
    float w = fmaxf(__fsub_rn(rx, lx), 0.0f);
    float h = fmaxf(__fsub_rn(ry, ly), 0.0f);
    float inter = __fmul_rn(w, h);
    float den = __fsub_rn(__fadd_rn(areaA, areaB), inter);
    return __fdividef(inter, den);
}
__device__ __forceinline__ float sl1(float x) {
    float ax = fabsf(x);
    return ax < 1.0f ? 0.5f * ax * ax : ax - 0.5f;
}
__device__ __forceinline__ float bce(float l, float t) {
    return fmaxf(l, 0.0f) - l * t + log1pf(expf(-fabsf(l)));
}

struct ShA { float4 abox[CHUNK]; float aarea[CHUNK]; };                       // 10240 B
struct ShD { float miou[KMAX]; unsigned char gi[KMAX]; short pl[KMAX]; };     //  7168 B

// acc: 4 det_ce, 5 det_sel, 6 det_reg, 7 det_selfg, 8 vis_sum, 9 amo_sum, 10 keep_cnt

// Blocks 0..NB1-1: per-gt max IoU over anchor range -> bmaxT[b][gt] (plain stores;
// published by kernel-boundary flush). Block NB1: det matching + fg/bg wave-scan
// selection -> pinfo, acc[5,7,10]; zeroes acc[4,6,8,9] for k_main's tail role.
__global__ __launch_bounds__(BS) void k_pass1(
    const float4* __restrict__ anchors, const float4* __restrict__ gt,
    const int* __restrict__ gt_labels, const float4* __restrict__ proposals,
    int N, int M, int K, int AP,
    float* __restrict__ bmaxT, float* acc, int* pinfo)
{
    __shared__ __align__(16) char shbuf[sizeof(ShA)];
    __shared__ float4 sgt[GTMAX];
    __shared__ float sarea[GTMAX];
    __shared__ int   slab[GTMAX];
    __shared__ float swm[4 * 64];
    __shared__ float sred[4];
    __shared__ int   swtot[4];
    ShA* SA = (ShA*)shbuf;
    ShD* SD = (ShD*)shbuf;

    const int b = blockIdx.x, t = threadIdx.x;
    const int wave = t >> 6, lane = t & 63;

    if (t < M) {
        float4 g = gt[t];
        sgt[t] = g; sarea[t] = box_area(g); slab[t] = gt_labels[t];
    }
    __syncthreads();

    if (b < NB1) {
        // ---------- per-gt max over this block's anchor range ----------
        int base = b * AP;
        int end = min(N, base + AP);
        float4 g; float ga = 0.0f;
        bool gok = lane < M;
        if (gok) { g = sgt[lane]; ga = sarea[lane]; }
        float m = 0.0f;                          // IoU >= 0 always
        for (int tile = base; tile < end; tile += CHUNK) {
            int tcnt = min(CHUNK, end - tile);
            __syncthreads();
            for (int k = t; k < tcnt; k += BS) {
                float4 a = anchors[tile + k];
                SA->abox[k] = a;
                SA->aarea[k] = box_area(a);
            }
            __syncthreads();
            for (int k = wave; k < tcnt; k += 4) {   // wave-uniform broadcast
                float4 a = SA->abox[k];
                float aa = SA->aarea[k];
                if (gok) m = fmaxf(m, iou_f(a, aa, g, ga));
            }
        }
        swm[wave * 64 + lane] = m;
        __syncthreads();
        if (wave == 0) {
            float mm = fmaxf(fmaxf(swm[lane], swm[64 + lane]),
                             fmaxf(swm[128 + lane], swm[192 + lane]));
            bmaxT[b * GTMAX + lane] = mm;        // plain store; kernel-boundary flush
        }
    } else {
        // ---------- det matching + sampling (single block) ----------
        for (int p = t; p < K; p += BS) {
            float4 a = proposals[p];
            float areaA = box_area(a);
            float mx = -1.0f; int am = 0;
            for (int j = 0; j < M; ++j) {
                float v = iou_f(a, areaA, sgt[j], sarea[j]);
                if (v > mx) { mx = v; am = j; }
            }
            SD->miou[p] = mx; SD->gi[p] = (unsigned char)am;
            int pl = slab[am];
            if (mx < 0.5f) pl = 0;
            if (mx < 0.1f) pl = -1;
            SD->pl[p] = (short)pl;
        }
        __syncthreads();
        // wave-scan fg/bg sampling (4 contiguous p per thread)
        int myp0 = t * 4;
        int cf = 0, cb = 0;
        for (int e = 0; e < 4; ++e) {
            int p = myp0 + e;
            if (p < K) { int pl = SD->pl[p]; cf += (pl > 0); cb += (pl == 0); }
        }
        int packed = cf | (cb << 16);
        int scan = packed;
        for (int off = 1; off < 64; off <<= 1) {
            int n = __shfl_up(scan, off);
            if (lane >= off) scan += n;
        }
        if (lane == 63) swtot[wave] = scan;
        __syncthreads();
        int woff = 0, tot = 0;
        for (int w = 0; w < 4; ++w) { int v = swtot[w]; if (w < wave) woff += v; tot += v; }
        int excl = scan - packed + woff;
        int runf = excl & 0xffff, runb = (excl >> 16) & 0xffff;
        int totfg = tot & 0xffff, totbg = (tot >> 16) & 0xffff;
        int nfg = totfg < 32 ? totfg : 32;
        int nbg = 128 - nfg;
        int keeploc = 0;
        for (int e = 0; e < 4; ++e) {
            int p = myp0 + e;
            if (p < K) {
                int pl = SD->pl[p];
                int sf = 0, sb = 0;
                if (pl > 0)       { runf++; sf = (runf <= nfg); }
                else if (pl == 0) { runb++; sb = (runb <= nbg); }
                int kp = SD->miou[p] >= 0.5f ? 1 : 0;
                keeploc += kp;
                int lab = pl > 0 ? pl : 0;
                pinfo[p] = (int)SD->gi[p] | (lab << 6) | (sf << 13) | (sb << 14) | (kp << 15);
            }
        }
        for (int off = 32; off; off >>= 1) keeploc += __shfl_xor(keeploc, off);
        if (lane == 0) sred[wave] = (float)keeploc;
        __syncthreads();
        if (t == 0) {
            acc[7]  = (float)nfg;
            acc[5]  = (float)(nfg + (totbg < nbg ? totbg : nbg));
            acc[10] = sred[0] + sred[1] + sred[2] + sred[3];
            acc[4] = 0.0f; acc[6] = 0.0f; acc[8] = 0.0f; acc[9] = 0.0f;
        }
    }
}

// Fused main kernel (round-6-proven structure; tail batched TPB proposals/block).
// Blocks < NB2 (RPN role): reduce bmaxT -> smaxpg, grid-stride RPN loss -> ppart.
// Blocks >= NB2: proposals p in [ (b-NB2)*TPB, ... ): det CE (parallel over C),
//   det reg, mask loss, accumulated via device atomicAdd into acc[4,6,8,9].
__global__ __launch_bounds__(BS) void k_main(
    const float4* __restrict__ anchors, const float4* __restrict__ preds,
    const float2* __restrict__ cls, const float4* __restrict__ gt,
    int N, int M, int K, int C, int H,
    const float* __restrict__ bmaxT, float* __restrict__ ppart,
    const float* __restrict__ vism, const float* __restrict__ amom,
    const float* __restrict__ mvl, const float* __restrict__ mal,
    const float4* __restrict__ proposals, const int* __restrict__ pinfo,
    const float* __restrict__ roi_cls, const float* __restrict__ roi_deltas,
    const int* __restrict__ gt_labels, float* acc)
{
    const int b = blockIdx.x, t = threadIdx.x;
    const int wave = t >> 6, lane = t & 63;

    if (b < NB2) {
        // ================= RPN role =================
        __shared__ float4 sgt[GTMAX];
        __shared__ float2 sgp[GTMAX];        // .x = area, .y = gmax
        __shared__ float swm[256];
        __shared__ float sacc[4];
        float4 gg; float garea = 0.0f;
        if (t < M) {
            gg = gt[t];
            garea = box_area(gg);
            sgt[t] = gg;
        }
        // per-block gmax reduction from bmaxT (L2/L3-hot, coalesced; proven r6)
        {
            int j = t & 63, part = t >> 6;
            float mm = 0.0f;
            int r0 = part * (NB1 / 4);
            for (int i = r0; i < r0 + NB1 / 4; ++i)
                mm = fmaxf(mm, bmaxT[i * GTMAX + j]);
            swm[t] = mm;
        }
        if (t < 4) sacc[t] = 0.0f;
        __syncthreads();
        if (t < M) {
            float mm = fmaxf(fmaxf(swm[t], swm[64 + t]),
                             fmaxf(swm[128 + t], swm[192 + t]));
            sgp[t] = make_float2(garea, mm);
        }
        __syncthreads();

        float ce = 0.f, valid = 0.f, pos = 0.f, reg = 0.f;
        for (int i = b * BS + t; i < N; i += NB2 * BS) {
            float4 a = anchors[i];
            float areaA = box_area(a);
            float2 x = cls[i];                    // hoisted
            float maxiou = -1.0f; int arg = 0; bool force = false;
            for (int j = 0; j < M; ++j) {
                float2 gp = sgp[j];
                float v = iou_f(a, areaA, sgt[j], gp.x);
                if (v > maxiou) { maxiou = v; arg = j; }
                force = force || (v == gp.y);
            }
            int label = force ? 1 : (maxiou >= 0.7f ? 1 : (maxiou <= 0.3f ? 0 : -1));
            if (label >= 0) {
                valid += 1.0f;
                float m = fmaxf(x.x, x.y);
                float lse = m + __logf(__expf(x.x - m) + __expf(x.y - m));
                ce += lse - (label == 1 ? x.y : x.x);
            }
            if (label == 1) {
                pos += 1.0f;
                float4 g = sgt[arg];
                float rw = a.z - a.x, rh = a.w - a.y;
                float t0 = ((g.x + g.z) * 0.5f - (a.x + a.z) * 0.5f) / rw;
                float t1 = ((g.y + g.w) * 0.5f - (a.y + a.w) * 0.5f) / rh;
                float t2 = logf((g.z - g.x) / rw);
                float t3 = logf((g.w - g.y) / rh);
                float4 p = preds[i];
                reg += sl1(p.x - t0) + sl1(p.y - t1) + sl1(p.z - t2) + sl1(p.w - t3);
            }
        }
        for (int off = 32; off; off >>= 1) {
            ce += __shfl_xor(ce, off); valid += __shfl_xor(valid, off);
            pos += __shfl_xor(pos, off); reg += __shfl_xor(reg, off);
        }
        if (lane == 0) {
            atomicAdd(&sacc[0], ce); atomicAdd(&sacc[1], valid);
            atomicAdd(&sacc[2], reg); atomicAdd(&sacc[3], pos);
        }
        __syncthreads();
        if (t == 0) {
            ppart[0 * NB2 + b] = sacc[0];
            ppart[1 * NB2 + b] = sacc[1];
            ppart[2 * NB2 + b] = sacc[2];
            ppart[3 * NB2 + b] = sacc[3];
        }
    } else {
        // ================= tail role: TPB proposals per block =================
        __shared__ float sredM[4], sredE[4];
        int p0 = (b - NB2) * TPB;
        for (int e = 0; e < TPB; ++e) {
            int p = p0 + e;
            if (p >= K) break;
            __syncthreads();                 // LDS reuse fence between proposals
            int info = pinfo[p];
            bool sf = (info >> 13) & 1, sb = (info >> 14) & 1, kp = (info >> 15) & 1;
            if (!(sf | sb | kp)) continue;   // block-uniform
            int gi = info & 63;
            int lab = (info >> 6) & 0x7f;

            if (sf || sb) {   // detection CE, parallel over classes
                const float* row = roi_cls + (size_t)p * C;
                float v = (t < C) ? row[t] : -INFINITY;
                float m = v;
                for (int off = 32; off; off >>= 1) m = fmaxf(m, __shfl_xor(m, off));
                if (lane == 0) sredM[wave] = m;
                __syncthreads();
                m = fmaxf(fmaxf(sredM[0], sredM[1]), fmaxf(sredM[2], sredM[3]));
                float ex = (t < C) ? __expf(v - m) : 0.0f;
                for (int off = 32; off; off >>= 1) ex += __shfl_xor(ex, off);
                if (lane == 0) sredE[wave] = ex;
                __syncthreads();
                if (t == 0) {
                    float lse = m + __logf(sredE[0] + sredE[1] + sredE[2] + sredE[3]);
                    atomicAdd(&acc[4], lse - row[lab]);
                }
            }
            if (sf && t == 0) {   // detection reg
                float4 a = proposals[p];
                float4 g = gt[gi];
                float rw = a.z - a.x, rh = a.w - a.y;
                float t0 = ((g.x + g.z) * 0.5f - (a.x + a.z) * 0.5f) / rw;
                float t1 = ((g.y + g.w) * 0.5f - (a.y + a.w) * 0.5f) / rh;
                float t2 = logf((g.z - g.x) / rw);
                float t3 = logf((g.w - g.y) / rh);
                const float* pr = roi_deltas + ((size_t)p * C + lab) * 4;
                float r = sl1(pr[0] - t0) + sl1(pr[1] - t1) + sl1(pr[2] - t2) + sl1(pr[3] - t3);
                atomicAdd(&acc[6], r);
            }
            if (kp) {   // mask loss (bilinear roi-align + bce)
                int mlab = gt_labels[gi];
                float4 r = proposals[p];
                float x1 = r.x - 0.5f, y1 = r.y - 0.5f;
                float bw = (r.z - r.x) / (float)MS;
                float bh = (r.w - r.y) / (float)MS;
                const float* vm = vism + (size_t)gi * H * H;
                const float* am = amom + (size_t)gi * H * H;
                const float* lv = mvl + ((size_t)p * C + mlab) * MSQ;
                const float* la = mal + ((size_t)p * C + mlab) * MSQ;
                float sv = 0.f, sa = 0.f;
                for (int px = t; px < MSQ; px += BS) {
                    int gx = px % MS, gy = px / MS;
                    float X = x1 + ((float)gx + 0.5f) * bw;
                    float Y = y1 + ((float)gy + 0.5f) * bh;
                    bool valid = (Y > -1.0f) && (Y < (float)H) && (X > -1.0f) && (X < (float)H);
                    float Yc = fminf(fmaxf(Y, 0.0f), (float)(H - 1));
                    float Xc = fminf(fmaxf(X, 0.0f), (float)(H - 1));
                    int y0 = (int)floorf(Yc), x0 = (int)floorf(Xc);
                    int y1i = min(y0 + 1, H - 1), x1i = min(x0 + 1, H - 1);
                    float ly = Yc - (float)y0, lx = Xc - (float)x0;
                    float w00 = (1.f - ly) * (1.f - lx), w01 = (1.f - ly) * lx;
                    float w10 = ly * (1.f - lx), w11 = ly * lx;
                    float tv = vm[y0 * H + x0] * w00 + vm[y0 * H + x1i] * w01 +
                               vm[y1i * H + x0] * w10 + vm[y1i * H + x1i] * w11;
                    float ta = am[y0 * H + x0] * w00 + am[y0 * H + x1i] * w01 +
                               am[y1i * H + x0] * w10 + am[y1i * H + x1i] * w11;
                    if (!valid) { tv = 0.f; ta = 0.f; }
                    sv += bce(lv[px], tv);
                    sa += bce(la[px], ta);
                }
                for (int off = 32; off; off >>= 1) {
                    sv += __shfl_xor(sv, off);
                    sa += __shfl_xor(sa, off);
                }
                if (lane == 0) { sredM[wave] = sv; sredE[wave] = sa; }
                __syncthreads();
                if (t == 0) {
                    atomicAdd(&acc[8], sredM[0] + sredM[1] + sredM[2] + sredM[3]);
                    atomicAdd(&acc[9], sredE[0] + sredE[1] + sredE[2] + sredE[3]);
                }
            }
        }
    }
}

// Sum rpn partials (wave w owns quantity q=w) and combine all losses.
__global__ __launch_bounds__(BS) void k_final(
    const float* __restrict__ ppart, const float* __restrict__ acc, float* out)
{
    __shared__ float sq[4];
    int t = threadIdx.x;
    int wave = t >> 6, lane = t & 63;
    float s = 0.f;
    for (int b = lane; b < NB2; b += 64) s += ppart[wave * NB2 + b];
    for (int off = 32; off; off >>= 1) s += __shfl_xor(s, off);
    if (lane == 0) sq[wave] = s;
    __syncthreads();
    if (t == 0) {
        float rpn_cls = sq[0] / fmaxf(sq[1], 1.0f);
        float rpn_reg = sq[2] / fmaxf(sq[3] * 4.0f, 1.0f);
        float det_cls = acc[4] / fmaxf(acc[5], 1.0f);
        float det_reg = acc[6] / fmaxf(acc[7] * 4.0f, 1.0f);
        float den = fmaxf(acc[10], 1.0f) * (float)MSQ;
        out[0] = rpn_cls + rpn_reg + det_cls + det_reg + acc[8] / den + acc[9] / den;
    }
}

extern "C" void kernel_launch(void* const* d_in, const int* in_sizes, int n_in,
                              void* d_out, int out_size, void* d_ws, size_t ws_size,
                              hipStream_t stream) {
    const float2* rpn_cls   = (const float2*)d_in[0];
    const float4* rpn_pred  = (const float4*)d_in[1];
    const float4* anchors   = (const float4*)d_in[2];
    const float4* gt        = (const float4*)d_in[3];
    const int*    gt_labels = (const int*)d_in[4];
    const float*  roi_cls   = (const float*)d_in[5];
    const float*  roi_deltas= (const float*)d_in[6];
    const float4* proposals = (const float4*)d_in[7];
    const float*  mvl       = (const float*)d_in[8];
    const float*  mal       = (const float*)d_in[9];
    const float*  vism      = (const float*)d_in[10];
    const float*  amom      = (const float*)d_in[11];

    int N = in_sizes[0] / 2;
    int M = in_sizes[3] / 4;
    int K = in_sizes[7] / 4;
    int C = in_sizes[5] / K;
    int HW = in_sizes[10] / M;
    int H = (int)(sqrt((double)HW) + 0.5);

    float* wsf   = (float*)d_ws;
    float* acc   = wsf;                          // 16 floats
    float* ppart = wsf + 16;                     // 4*NB2 = 2048
    float* bmaxT = wsf + 16 + 4 * NB2;           // NB1*64 = 32768
    int*   pinfo = (int*)(bmaxT + NB1 * GTMAX);  // K ints
    float* out   = (float*)d_out;

    int AP  = (N + NB1 - 1) / NB1;               // anchors per pass1 block
    int NBT = (K + TPB - 1) / TPB;               // tail blocks

    k_pass1<<<NB1 + 1, BS, 0, stream>>>(anchors, gt, gt_labels, proposals,
                                        N, M, K, AP, bmaxT, acc, pinfo);
    k_main<<<NB2 + NBT, BS, 0, stream>>>(anchors, rpn_pred, rpn_cls, gt,
                                         N, M, K, C, H, bmaxT, ppart,
                                         vism, amom, mvl, mal, proposals, pinfo,
                                         roi_cls, roi_deltas, gt_labels, acc);
    k_final<<<1, BS, 0, stream>>>(ppart, acc, out);
}